// Round 5
// baseline (239.886 us; speedup 1.0000x reference)
//
#include <hip/hip_runtime.h>

// Convex upsample, fused bf16-MFMA implicit GEMM, round 5 (r4 + compile fix).
//   prep:          w1/w2 -> bf16 frag layouts; zero NHWC pad ring.
//   nchw_to_nhwc:  feat NCHW f32 -> padded NHWC bf16, packed bf16x2 converts,
//                  conflict-free uint LDS transpose (stride 33), 2 h-rows/block.
//   main:          16x16-px tile, 512 thr (8 waves), feat tile via
//                  global_load_lds dwordx4 (XOR-swizzled), GEMM1 conv3x3 ->
//                  relu -> sH overlay -> GEMM2 1x1 (n-tile==tap) -> register
//                  softmax -> convex combine -> coalesced shuffled store.
// Fallback path (small ws): round-2 self-staged kernel.

using frag_ab = __attribute__((ext_vector_type(8))) short;   // 8 bf16
using frag_cd = __attribute__((ext_vector_type(4))) float;   // 4 f32
typedef __attribute__((ext_vector_type(8))) unsigned short ushort8;

static __device__ __forceinline__ unsigned short f2bf(float f) {
    unsigned u = __builtin_bit_cast(unsigned, f);
    u += 0x7fff + ((u >> 16) & 1);          // RNE
    return (unsigned short)(u >> 16);
}
static __device__ __forceinline__ unsigned int pkbf(float lo, float hi) {
    return (unsigned int)f2bf(lo) | ((unsigned int)f2bf(hi) << 16);
}

// ---------------- prep: weights + NHWC pad ring ----------------
__global__ void prep(const float* __restrict__ w1, const float* __restrict__ w2,
                     unsigned short* __restrict__ w1bf, unsigned short* __restrict__ w2bf,
                     unsigned short* __restrict__ nhwc, int do_pad) {
    int i = blockIdx.x * 256 + threadIdx.x;
    if (i < 36864) {   // ((tap*2+kh)*4+q)*512 + oc*8 + j
        int j = i & 7, oc = (i >> 3) & 63, g = i >> 9;
        int q = g & 3, kh = (g >> 2) & 1, tap = g >> 3;
        int ic = kh * 32 + q * 8 + j;
        w1bf[i] = f2bf(w1[(oc * 64 + ic) * 9 + (tap / 3) * 3 + (tap % 3)]);
    }
    if (i < 9216) {    // ((kh*4+q)*144 + ch)*8 + j
        int j = i & 7, ch = (i >> 3) % 144, g = (i >> 3) / 144;
        int q = g & 3, kh = g >> 2;
        w2bf[i] = f2bf(w2[ch * 64 + (kh * 32 + q * 8 + j)]);
    }
    if (do_pad && i < 69888) {   // rows {0,129} all w; cols {0,417} rows 1..128
        int b = i / 8736, rem = i - b * 8736;
        int pos = rem >> 3, pack = rem & 7;
        int row, w;
        if (pos < 836) { row = (pos < 418) ? 0 : 129; w = (pos < 418) ? pos : pos - 418; }
        else           { int t = pos - 836; row = 1 + (t >> 1); w = (t & 1) ? 417 : 0; }
        ushort8 z = {0, 0, 0, 0, 0, 0, 0, 0};
        *(ushort8*)&nhwc[(((size_t)b * 130 + row) * 418 + w) * 64 + pack * 8] = z;
    }
}

// ---------------- feat NCHW f32 -> padded NHWC bf16 (v2) ----------------
__global__ __launch_bounds__(256, 8) void nchw_to_nhwc(const float* __restrict__ feat,
                                                       unsigned short* __restrict__ nhwc) {
    __shared__ unsigned int sT[2][32 * 33];   // [hh][w][cpair], stride 33
    const int b = blockIdx.z, h0 = blockIdx.y * 2, w0 = blockIdx.x * 32;
    const int tid = threadIdx.x;
    const int cpair = tid >> 3;        // 0..31 -> c = 2*cpair, 2*cpair+1
    const int wseg  = tid & 7;         // w = wseg*4 .. +3

    #pragma unroll
    for (int hh = 0; hh < 2; ++hh) {
        const float* s0 = feat + (((size_t)b * 64 + 2 * cpair) * 128 + (h0 + hh)) * 416
                               + w0 + wseg * 4;
        float4 e = *(const float4*)s0;                    // channel 2*cpair
        float4 o = *(const float4*)(s0 + 416 * 128);      // channel 2*cpair+1
        sT[hh][(wseg * 4 + 0) * 33 + cpair] = pkbf(e.x, o.x);
        sT[hh][(wseg * 4 + 1) * 33 + cpair] = pkbf(e.y, o.y);
        sT[hh][(wseg * 4 + 2) * 33 + cpair] = pkbf(e.z, o.z);
        sT[hh][(wseg * 4 + 3) * 33 + cpair] = pkbf(e.w, o.w);
    }
    __syncthreads();
    const int w = tid >> 3, j = tid & 7;    // out chunk: 8 channels at c0 = j*8
    #pragma unroll
    for (int hh = 0; hh < 2; ++hh) {
        uint4 v;
        v.x = sT[hh][w * 33 + j * 4 + 0];
        v.y = sT[hh][w * 33 + j * 4 + 1];
        v.z = sT[hh][w * 33 + j * 4 + 2];
        v.w = sT[hh][w * 33 + j * 4 + 3];
        *(uint4*)&nhwc[(((size_t)b * 130 + h0 + hh + 1) * 418 + (w0 + w + 1)) * 64 + j * 8] = v;
    }
}

// ---------------- main fused kernel: 16x16 tile, 512 threads ----------------
__global__ __launch_bounds__(512, 4) void convex_up_mfma3(
    const float* __restrict__ depth, const unsigned short* __restrict__ nhwc,
    const unsigned short* __restrict__ w1bf, const unsigned short* __restrict__ w2bf,
    float* __restrict__ out)
{
    constexpr int H = 128, W = 416, OW = 1664;
    constexpr int RS = 418 * 64;                         // padded NHWC row stride

    __shared__ __align__(16) unsigned short sF[2592 * 8];  // 41472 B: [r18][col18][icc8 swz][8]
    __shared__ float sD[18 * 18];

    const int tid  = threadIdx.x;
    const int wv   = tid >> 6;        // 0..7
    const int lane = tid & 63;
    const int q    = lane >> 4;
    const int ln   = lane & 15;
    const int bw = blockIdx.x, bh = blockIdx.y, b = blockIdx.z;
    const int h0 = bh * 16, w0 = bw * 16;

    // depth tile (18x18 halo, zero-pad)
    if (tid < 324) {
        int lr = tid / 18, lc = tid % 18;
        int gh = h0 - 1 + lr, gw = w0 - 1 + lc;
        float v = 0.f;
        if ((unsigned)gh < (unsigned)H && (unsigned)gw < (unsigned)W)
            v = depth[((size_t)b * H + gh) * W + gw];
        sD[tid] = v;
    }

    // feat tile: 2592 16B-chunks via global_load_lds
    const unsigned short* gbase = nhwc + ((size_t)(b * 130 + h0) * 418 + w0) * 64;
    #pragma unroll
    for (int k = 0; k < 6; ++k) {
        int i = wv + 8 * k;
        int c = i * 64 + lane;
        if (c < 2592) {
            int r = c / 144, m = c - r * 144;
            int col = m >> 3, iccs = m & 7;
            int icc = iccs ^ (col & 7);       // XOR swizzle (source side)
            const unsigned short* g = gbase + (size_t)r * RS + col * 64 + icc * 8;
            __builtin_amdgcn_global_load_lds((const __attribute__((address_space(1))) void*)g,
                                             (__attribute__((address_space(3))) void*)&sF[c * 8],
                                             16, 0, 0);
        }
    }
    __syncthreads();

    // ---- GEMM1: conv3x3, wave owns px rows 2wv, 2wv+1 x 64 oc ----
    frag_cd acc1[2][4];
    #pragma unroll
    for (int mt = 0; mt < 2; ++mt)
        #pragma unroll
        for (int nt = 0; nt < 4; ++nt) acc1[mt][nt] = frag_cd{0.f, 0.f, 0.f, 0.f};

    #pragma unroll
    for (int tap = 0; tap < 9; ++tap) {
        const int ky = tap / 3, kx = tap % 3;
        #pragma unroll
        for (int kh = 0; kh < 2; ++kh) {
            frag_ab a[2];
            #pragma unroll
            for (int mt = 0; mt < 2; ++mt) {
                int r = 2 * wv + mt + ky, col = ln + kx;
                int slot = (r * 18 + col) * 8 + ((kh * 4 + q) ^ (col & 7));
                a[mt] = *(const frag_ab*)&sF[slot * 8];
            }
            frag_ab bf[4];
            #pragma unroll
            for (int nt = 0; nt < 4; ++nt)
                bf[nt] = *(const frag_ab*)&w1bf[(size_t)((tap * 2 + kh) * 4 + q) * 512 + (nt * 16 + ln) * 8];
            #pragma unroll
            for (int mt = 0; mt < 2; ++mt)
                #pragma unroll
                for (int nt = 0; nt < 4; ++nt)
                    acc1[mt][nt] = __builtin_amdgcn_mfma_f32_16x16x32_bf16(a[mt], bf[nt], acc1[mt][nt], 0, 0, 0);
        }
    }

    __syncthreads();   // all waves done reading sF; overlay per-wave sH

    unsigned short* sH = sF + wv * 2304;   // [px32][72] bf16, 4608 B slice
    #pragma unroll
    for (int mt = 0; mt < 2; ++mt)
        #pragma unroll
        for (int nt = 0; nt < 4; ++nt)
            #pragma unroll
            for (int r = 0; r < 4; ++r)
                sH[(mt * 16 + q * 4 + r) * 72 + nt * 16 + ln] = f2bf(fmaxf(acc1[mt][nt][r], 0.f));
    // same-wave LDS RAW: compiler-inserted lgkmcnt, no barrier needed

    // ---- GEMM2: logits, n-tile == tap ----
    frag_cd acc2[2][9];
    #pragma unroll
    for (int mt = 0; mt < 2; ++mt)
        #pragma unroll
        for (int nt = 0; nt < 9; ++nt) acc2[mt][nt] = frag_cd{0.f, 0.f, 0.f, 0.f};

    #pragma unroll
    for (int kh = 0; kh < 2; ++kh) {
        frag_ab a2[2];
        #pragma unroll
        for (int mt = 0; mt < 2; ++mt)
            a2[mt] = *(const frag_ab*)&sH[(mt * 16 + ln) * 72 + kh * 32 + q * 8];
        #pragma unroll
        for (int nt = 0; nt < 9; ++nt) {
            frag_ab b2 = *(const frag_ab*)&w2bf[(size_t)((kh * 4 + q) * 144 + nt * 16 + ln) * 8];
            acc2[0][nt] = __builtin_amdgcn_mfma_f32_16x16x32_bf16(a2[0], b2, acc2[0][nt], 0, 0, 0);
            acc2[1][nt] = __builtin_amdgcn_mfma_f32_16x16x32_bf16(a2[1], b2, acc2[1][nt], 0, 0, 0);
        }
    }

    // ---- softmax over 9 taps + convex combine; stage into own slice ----
    float* sOutw = (float*)sH;   // [px32][17] f32 (max 542 floats < 1152) in own slice
    #pragma unroll
    for (int mt = 0; mt < 2; ++mt) {
        const int prow = 2 * wv + mt;
        #pragma unroll
        for (int r = 0; r < 4; ++r) {
            const int pcol = q * 4 + r;
            float lg[9];
            #pragma unroll
            for (int t = 0; t < 9; ++t) lg[t] = acc2[mt][t][r];
            float mx = lg[0];
            #pragma unroll
            for (int t = 1; t < 9; ++t) mx = fmaxf(mx, lg[t]);
            float sum = 0.f, up = 0.f;
            #pragma unroll
            for (int t = 0; t < 9; ++t) {
                float e = __expf(lg[t] - mx);
                sum += e;
                up  += e * sD[(prow + t / 3) * 18 + (pcol + t % 3)];
            }
            sOutw[(mt * 16 + pcol) * 17 + ln] = up / sum;
        }
    }
    float* outb = out + (size_t)b * 512 * OW + (size_t)(h0 + 2 * wv) * 4 * OW + w0 * 4;
    const int row_o = lane >> 3;
    const int mt_o  = row_o >> 2, sy_o = row_o & 3;
    #pragma unroll
    for (int v = 0; v < 2; ++v) {
        float4 o;
        #pragma unroll
        for (int e = 0; e < 4; ++e) {
            int j = (lane & 7) * 8 + v * 4 + e;
            o[e] = sOutw[(mt_o * 16 + (j >> 2)) * 17 + sy_o * 4 + (j & 3)];
        }
        *(float4*)&outb[(size_t)row_o * OW + (lane & 7) * 8 + v * 4] = o;
    }
}

// ---------------- fallback (round-2 kernel, self-staged) ----------------
__global__ __launch_bounds__(256, 3) void convex_up_mfma_fb(
    const float* __restrict__ depth, const float* __restrict__ feat,
    const unsigned short* __restrict__ w1bf, const unsigned short* __restrict__ w2bf,
    float* __restrict__ out)
{
    constexpr int H = 128, W = 416, OW = 1664;
    __shared__ unsigned short sF[8 * 10 * 18 * 8];
    __shared__ unsigned short sH[4][32 * 72];
    __shared__ float sD[10 * 18];
    const int tid = threadIdx.x, wv = tid >> 6, lane = tid & 63;
    const int q = lane >> 4, ln = lane & 15;
    const int bw = blockIdx.x, bh = blockIdx.y, b = blockIdx.z;
    const int h0 = bh * 8, w0 = bw * 16;
    if (tid < 180) {
        int lr = tid / 18, lc = tid % 18;
        int gh = h0 - 1 + lr, gw = w0 - 1 + lc;
        float v = 0.f;
        if ((unsigned)gh < (unsigned)H && (unsigned)gw < (unsigned)W)
            v = depth[((size_t)b * H + gh) * W + gw];
        sD[tid] = v;
    }
    for (int idx = tid; idx < 11520; idx += 256) {
        int ic = idx / 180, rem = idx - ic * 180;
        int lr = rem / 18, lc = rem - lr * 18;
        int gh = h0 - 1 + lr, gw = w0 - 1 + lc;
        float v = 0.f;
        if ((unsigned)gh < (unsigned)H && (unsigned)gw < (unsigned)W)
            v = feat[(((size_t)b * 64 + ic) * H + gh) * W + gw];
        sF[(((ic >> 3) * 10 + lr) * 18 + lc) * 8 + (ic & 7)] = f2bf(v);
    }
    __syncthreads();
    frag_cd acc1[2][4];
    for (int mt = 0; mt < 2; ++mt) for (int nt = 0; nt < 4; ++nt) acc1[mt][nt] = frag_cd{0.f,0.f,0.f,0.f};
    #pragma unroll
    for (int tap = 0; tap < 9; ++tap) {
        const int ky = tap / 3, kx = tap % 3;
        #pragma unroll
        for (int kh = 0; kh < 2; ++kh) {
            frag_ab a[2];
            #pragma unroll
            for (int mt = 0; mt < 2; ++mt)
                a[mt] = *(const frag_ab*)&sF[(((kh * 4 + q) * 10 + 2 * wv + mt + ky) * 18 + ln + kx) * 8];
            frag_ab bf[4];
            #pragma unroll
            for (int nt = 0; nt < 4; ++nt)
                bf[nt] = *(const frag_ab*)&w1bf[(size_t)((tap * 2 + kh) * 4 + q) * 512 + (nt * 16 + ln) * 8];
            #pragma unroll
            for (int mt = 0; mt < 2; ++mt)
                #pragma unroll
                for (int nt = 0; nt < 4; ++nt)
                    acc1[mt][nt] = __builtin_amdgcn_mfma_f32_16x16x32_bf16(a[mt], bf[nt], acc1[mt][nt], 0, 0, 0);
        }
    }
    #pragma unroll
    for (int mt = 0; mt < 2; ++mt)
        #pragma unroll
        for (int nt = 0; nt < 4; ++nt)
            #pragma unroll
            for (int r = 0; r < 4; ++r)
                sH[wv][(mt * 16 + q * 4 + r) * 72 + nt * 16 + ln] = f2bf(fmaxf(acc1[mt][nt][r], 0.f));
    frag_cd acc2[2][9];
    for (int mt = 0; mt < 2; ++mt) for (int nt = 0; nt < 9; ++nt) acc2[mt][nt] = frag_cd{0.f,0.f,0.f,0.f};
    #pragma unroll
    for (int kh = 0; kh < 2; ++kh) {
        frag_ab a2[2];
        #pragma unroll
        for (int mt = 0; mt < 2; ++mt)
            a2[mt] = *(const frag_ab*)&sH[wv][(mt * 16 + ln) * 72 + kh * 32 + q * 8];
        #pragma unroll
        for (int nt = 0; nt < 9; ++nt) {
            frag_ab b2 = *(const frag_ab*)&w2bf[(size_t)((kh * 4 + q) * 144 + nt * 16 + ln) * 8];
            acc2[0][nt] = __builtin_amdgcn_mfma_f32_16x16x32_bf16(a2[0], b2, acc2[0][nt], 0, 0, 0);
            acc2[1][nt] = __builtin_amdgcn_mfma_f32_16x16x32_bf16(a2[1], b2, acc2[1][nt], 0, 0, 0);
        }
    }
    float* sOutw = (float*)&sH[wv][0];
    #pragma unroll
    for (int mt = 0; mt < 2; ++mt) {
        const int prow = 2 * wv + mt;
        #pragma unroll
        for (int r = 0; r < 4; ++r) {
            const int pcol = q * 4 + r;
            float lg[9];
            #pragma unroll
            for (int t = 0; t < 9; ++t) lg[t] = acc2[mt][t][r];
            float mx = lg[0];
            #pragma unroll
            for (int t = 1; t < 9; ++t) mx = fmaxf(mx, lg[t]);
            float sum = 0.f, up = 0.f;
            #pragma unroll
            for (int t = 0; t < 9; ++t) {
                float e = __expf(lg[t] - mx);
                sum += e; up += e * sD[(prow + t / 3) * 18 + (pcol + t % 3)];
            }
            sOutw[(mt * 16 + pcol) * 17 + ln] = up / sum;
        }
    }
    float* outb = out + (size_t)b * 512 * OW + (size_t)(h0 + 2 * wv) * 4 * OW + w0 * 4;
    const int row_o = lane >> 3, mt_o = row_o >> 2, sy_o = row_o & 3;
    #pragma unroll
    for (int v = 0; v < 2; ++v) {
        float4 o;
        #pragma unroll
        for (int e = 0; e < 4; ++e) {
            int j = (lane & 7) * 8 + v * 4 + e;
            o[e] = sOutw[(mt_o * 16 + (j >> 2)) * 17 + sy_o * 4 + (j & 3)];
        }
        *(float4*)&outb[(size_t)row_o * OW + (lane & 7) * 8 + v * 4] = o;
    }
}

extern "C" void kernel_launch(void* const* d_in, const int* in_sizes, int n_in,
                              void* d_out, int out_size, void* d_ws, size_t ws_size,
                              hipStream_t stream) {
    const float* depth = (const float*)d_in[0];
    const float* feat  = (const float*)d_in[1];
    const float* w1    = (const float*)d_in[2];
    const float* w2    = (const float*)d_in[3];
    float* out = (float*)d_out;

    const size_t NHWC_USHORTS = (size_t)8 * 130 * 418 * 64;        // 27,827,200
    const size_t NEED = NHWC_USHORTS * 2 + (36864 + 9216) * 2;     // ~55.75 MB

    if (ws_size >= NEED) {
        unsigned short* nhwc = (unsigned short*)d_ws;
        unsigned short* w1bf = nhwc + NHWC_USHORTS;
        unsigned short* w2bf = w1bf + 36864;
        prep<<<273, 256, 0, stream>>>(w1, w2, w1bf, w2bf, nhwc, 1);
        nchw_to_nhwc<<<dim3(13, 64, 8), 256, 0, stream>>>(feat, nhwc);
        convex_up_mfma3<<<dim3(26, 8, 8), dim3(512), 0, stream>>>(depth, nhwc, w1bf, w2bf, out);
    } else {
        unsigned short* w1bf = (unsigned short*)d_ws;
        unsigned short* w2bf = w1bf + 36864;
        prep<<<273, 256, 0, stream>>>(w1, w2, w1bf, w2bf, nullptr, 0);
        convex_up_mfma_fb<<<dim3(26, 16, 8), 256, 0, stream>>>(depth, feat, w1bf, w2bf, out);
    }
}